// Round 2
// baseline (254.079 us; speedup 1.0000x reference)
//
#include <hip/hip_runtime.h>

// HarmonicFullyConnectedTensorProduct, lmax=2, MUL=64, B=1024, 11 paths.
// out[z,w,k] += sum_{u,v,m,n} x1[z,u,m] x2[z,v,n] W[p,w,u,v] C_p[m,n,k]
//
// Round 10 = Round 9 resubmitted (R9 bench died at container level, no GPU
// diagnostics; kernel re-audited: LDS <= 32768 for all paths, uniform barriers,
// all global accesses in-bounds, aligned float4 slab loads).
// R9 changes vs R8 (183us, tp_main 89us @ VALU 37.6% / MFMA 8.6% / occ 36.9%):
//  - tform: k-pair packed FMA (v_pk_fma_f32 via __builtin_elementwise_fma) on a
//    [n][K1+1]-strided c1 slab + v_cvt_pk_bf16_f32 (HW RNE) -> ~35% fewer VALU
//    ops in the dominant phase.
//  - slab build: per-thread element map (sc1/C/x1 offsets) precomputed once per
//    block; refills are pure FMA+store (no div/mod in the loop).
//  - LDS 38144 -> 32768 (per-path UC retune) -> 5 blocks/CU (launch_bounds 256,5).
//  - reduce_out: usub split across 4 waves (35 loads/thread, 1024 blocks) + LDS
//    combine; prep_w uses cvt_pk.

#define NTHREADS 256
#define SMEM_BYTES 32768

typedef __attribute__((ext_vector_type(4))) float f32x4;
typedef __attribute__((ext_vector_type(2))) float f32x2;
typedef __attribute__((ext_vector_type(8))) short s16x8;

// ---------------- prep: W fp32 [p][w][u][v] -> bf16 [p][u][w][v] ----------------

__global__ __launch_bounds__(NTHREADS) void prep_w(const float* __restrict__ W,
                                                   unsigned short* __restrict__ Wb)
{
    int id = blockIdx.x * NTHREADS + threadIdx.x;   // (p,u,w,v4): 11*64*64*16
    int v4 = (id & 15) << 2;
    int w  = (id >> 4) & 63;
    int u  = (id >> 10) & 63;
    int p  = id >> 16;
    float4 f = *(const float4*)(W + (((size_t)p * 64 + w) * 64 + u) * 64 + v4);
    unsigned r0, r1;
    asm("v_cvt_pk_bf16_f32 %0, %1, %2" : "=v"(r0) : "v"(f.x), "v"(f.y));
    asm("v_cvt_pk_bf16_f32 %0, %1, %2" : "=v"(r1) : "v"(f.z), "v"(f.w));
    union { unsigned u2[2]; ushort4 h; } pk;
    pk.u2[0] = r0; pk.u2[1] = r1;
    *(ushort4*)(Wb + (((size_t)p * 64 + u) * 64 + w) * 64 + v4) = pk.h;
}

// ---------------- main ----------------

struct KArgs {
    const float*          x1[3];
    const float*          x2[3];
    const unsigned short* Wb;
    const float*          C[11];
    float*                part[11];   // per-path partials [4 usub][1024][64][K1]
};

// S1 = pad4(N1*KP), KP = (K1==1)?1:K1+1  (even stride so k-pairs are 8B aligned)
template <int M1, int N1, int K1, int ZT, int S1, int UC>
__device__ __forceinline__ void run_path(const float* __restrict__ x1g,
                                         const float* __restrict__ x2g,
                                         const unsigned short* __restrict__ Wbp,
                                         const float* __restrict__ Cg,
                                         float* __restrict__ partp,
                                         int local, char* __restrict__ smem)
{
    constexpr int KP   = (K1 == 1) ? 1 : (K1 + 1);
    constexpr int KN   = K1 * N1;             // valid c1 elements per (z,u)
    constexpr int NC   = ZT * K1 / 16;        // MFMA col-tiles
    constexpr bool EVEN = (NC % 2 == 0);
    constexpr int ROWT = EVEN ? 2 : 1;        // w-tiles per wave
    constexpr int COLT = EVEN ? NC / 2 : NC;  // col-tiles per wave
    constexpr int NI   = ZT / 4;              // T-form z-iters
    constexpr int SST  = UC * S1 + 4;         // sc1 z-stride (floats)
    constexpr int TROWS = ZT * K1;
    constexpr int TOT  = ZT * UC * KN;
    constexpr int NEL  = (TOT + NTHREADS - 1) / NTHREADS;

    float*          sC  = (float*)smem;                        // [<=125]
    float*          sc1 = (float*)(smem + 512);                // [ZT][SST]
    unsigned short* sT0 = (unsigned short*)(smem + 512 + ZT * SST * 4);
    // sT0: 2 buffers x TROWS x 72 bf16

    const int t = threadIdx.x, lane = t & 63, wave = t >> 6;
    const int ln = lane & 15, q = lane >> 4;
    const int ztile = local >> 2, usub = local & 3;
    const int z0 = ztile * ZT, u0 = usub * 16;

    for (int i = t; i < M1 * N1 * K1; i += NTHREADS) sC[i] = Cg[i];
    __syncthreads();

    // --- per-thread slab element map (decode div/mods run ONCE per block) ---
    int soff[NEL], doff[NEL], x1c[NEL];
#pragma unroll
    for (int l = 0; l < NEL; ++l) {
        int e = t + l * NTHREADS;
        if (e >= TOT) e = TOT - 1;              // duplicate write, benign
        const int z   = e / (UC * KN);
        const int rr_ = e - z * (UC * KN);
        const int uu2 = rr_ / KN;
        const int j   = rr_ - uu2 * KN;
        const int n   = j / K1;
        const int k   = j - n * K1;
        soff[l] = z * SST + uu2 * S1 + n * KP + k;
        doff[l] = n * K1 + k;                   // sC index = m*KN + doff
        x1c[l]  = (z * 64 + uu2) * M1;
    }

    // cooperative c1 slab build for u in [u0+us0, u0+us0+UC)
    auto build_slab = [&](int us0) {
        const float* x1b = x1g + ((size_t)z0 * 64 + u0 + us0) * M1;
#pragma unroll
        for (int l = 0; l < NEL; ++l) {
            const float* x1r = x1b + x1c[l];
            float s = 0.f;
#pragma unroll
            for (int m = 0; m < M1; ++m) s += x1r[m] * sC[m * KN + doff[l]];
            sc1[soff[l]] = s;
        }
    };

    // x2 for this thread's (z = i*4+wave, v = lane), reused across all u
    float xr[NI][N1];
#pragma unroll
    for (int i = 0; i < NI; ++i) {
        const float* xp = x2g + ((size_t)(z0 + i * 4 + wave) * 64 + lane) * N1;
#pragma unroll
        for (int n = 0; n < N1; ++n) xr[i][n] = xp[n];
    }

    // T-form for u-offset uf into buffer sTn
    auto tform = [&](int uf, unsigned short* sTn) {
        const int uus = uf & (UC - 1);
#pragma unroll
        for (int i = 0; i < NI; ++i) {
            const int z = i * 4 + wave;                 // wave-uniform
            const float* cp = &sc1[z * SST + uus * S1]; // broadcast reads
            float c1v[S1];
#pragma unroll
            for (int jj = 0; jj < S1 / 4; ++jj) {
                float4 f = ((const float4*)cp)[jj];
                c1v[jj * 4 + 0] = f.x; c1v[jj * 4 + 1] = f.y;
                c1v[jj * 4 + 2] = f.z; c1v[jj * 4 + 3] = f.w;
            }
            unsigned short* dst = sTn + lane;
            if constexpr (K1 == 1) {
                float s = 0.f;
#pragma unroll
                for (int n = 0; n < N1; ++n) s += xr[i][n] * c1v[n];
                unsigned rr; const float zz = 0.f;
                asm("v_cvt_pk_bf16_f32 %0, %1, %2" : "=v"(rr) : "v"(s), "v"(zz));
                dst[z * 72] = (unsigned short)rr;
            } else {
                constexpr int NPAIR = K1 / 2;           // K1 is odd: 5->2, 3->1
                f32x2 acc2[NPAIR];
                float accl = 0.f;
#pragma unroll
                for (int p2 = 0; p2 < NPAIR; ++p2) acc2[p2] = (f32x2){0.f, 0.f};
#pragma unroll
                for (int n = 0; n < N1; ++n) {
                    const float xv = xr[i][n];
                    const f32x2 bb = (f32x2){xv, xv};
#pragma unroll
                    for (int p2 = 0; p2 < NPAIR; ++p2) {
                        const f32x2 cc = (f32x2){c1v[n * KP + 2 * p2],
                                                 c1v[n * KP + 2 * p2 + 1]};
                        acc2[p2] = __builtin_elementwise_fma(bb, cc, acc2[p2]);
                    }
                    accl += xv * c1v[n * KP + K1 - 1];  // odd trailing k
                }
#pragma unroll
                for (int p2 = 0; p2 < NPAIR; ++p2) {
                    unsigned rr;
                    asm("v_cvt_pk_bf16_f32 %0, %1, %2"
                        : "=v"(rr) : "v"(acc2[p2].x), "v"(acc2[p2].y));
                    dst[(z * K1 + 2 * p2) * 72]     = (unsigned short)rr;
                    dst[(z * K1 + 2 * p2 + 1) * 72] = (unsigned short)(rr >> 16);
                }
                {
                    unsigned rr; const float zz = 0.f;
                    asm("v_cvt_pk_bf16_f32 %0, %1, %2"
                        : "=v"(rr) : "v"(accl), "v"(zz));
                    dst[(z * K1 + K1 - 1) * 72] = (unsigned short)rr;
                }
            }
        }
    };

    f32x4 acc[ROWT][COLT];
#pragma unroll
    for (int rt = 0; rt < ROWT; ++rt)
#pragma unroll
        for (int ci = 0; ci < COLT; ++ci) acc[rt][ci] = (f32x4){0.f, 0.f, 0.f, 0.f};

    build_slab(0);
    __syncthreads();
    tform(0, sT0);
    __syncthreads();

#pragma unroll 2
    for (int uu = 0; uu < 16; ++uu) {
        if (((uu + 1) & (UC - 1)) == 0 && (uu + 1) < 16) {
            // refill sc1 for next slab; prior readers finished before last barrier
            build_slab(uu + 1);
            __syncthreads();
        }
        const int cur = uu & 1;
        unsigned short* sTc = sT0 + cur * (TROWS * 72);
        unsigned short* sTn = sT0 + (cur ^ 1) * (TROWS * 72);

        // A-frags for THIS u straight from L2 (issued early = in-iter prefetch)
        const unsigned short* wsrc = Wbp + (size_t)(u0 + uu) * 4096;
        s16x8 areg[ROWT][2];
#pragma unroll
        for (int rt = 0; rt < ROWT; ++rt) {
            const int wt = EVEN ? ((wave >> 1) * 2 + rt) : wave;
#pragma unroll
            for (int s2 = 0; s2 < 2; ++s2)
                areg[rt][s2] = *(const s16x8*)(wsrc + (wt * 16 + ln) * 64 + s2 * 32 + q * 8);
        }

        // T-form next u (writes sTn) — overlaps with MFMA below in the pipes
        if (uu < 15) tform(uu + 1, sTn);

        // MFMA from sTc
#pragma unroll
        for (int ci = 0; ci < COLT; ++ci) {
            const int c = EVEN ? ((wave & 1) * COLT + ci) : ci;
            s16x8 bf0 = *(const s16x8*)&sTc[(c * 16 + ln) * 72 + q * 8];
            s16x8 bf1 = *(const s16x8*)&sTc[(c * 16 + ln) * 72 + 32 + q * 8];
#pragma unroll
            for (int rt = 0; rt < ROWT; ++rt) {
                acc[rt][ci] = __builtin_amdgcn_mfma_f32_16x16x32_bf16(
                    areg[rt][0], bf0, acc[rt][ci], 0, 0, 0);
                acc[rt][ci] = __builtin_amdgcn_mfma_f32_16x16x32_bf16(
                    areg[rt][1], bf1, acc[rt][ci], 0, 0, 0);
            }
        }
        __syncthreads();
    }

    // ---- epilogue: plain stores to per-(path,usub) partials (no atomics)
#pragma unroll
    for (int rt = 0; rt < ROWT; ++rt) {
        const int wt = EVEN ? ((wave >> 1) * 2 + rt) : wave;
#pragma unroll
        for (int ci = 0; ci < COLT; ++ci) {
            const int c = EVEN ? ((wave & 1) * COLT + ci) : ci;
            const int col = c * 16 + ln;
            const int z = col / K1, k = col - z * K1;
            float* op = partp + ((size_t)(usub * 1024 + z0 + z) * 64) * K1 + k;
#pragma unroll
            for (int r = 0; r < 4; ++r)
                op[(wt * 16 + q * 4 + r) * K1] = acc[rt][ci][r];
        }
    }
}

__global__ __launch_bounds__(NTHREADS, 5) void tp_main(KArgs a)
{
    __shared__ __align__(16) char smem[SMEM_BYTES];

    const int bid = blockIdx.x;
    // heavy-first: p2,p10,p5,p7,p6 (256 ea, ZT16), then p1,p8,p3,p9,p4,p0 (128 ea, ZT32)
    const int starts[12] = {0, 256, 512, 768, 1024, 1280, 1408, 1536, 1664, 1792, 1920, 2048};
    int idx = 0;
#pragma unroll
    for (int i = 1; i < 12; ++i) idx += (bid >= starts[i]) ? 1 : 0;
    const int local = bid - starts[idx];

    switch (idx) {            //  M1 N1 K1 ZT S1 UC    (S1 = pad4(N1*KP))
        case 0:  run_path<1,5,5,16,32, 4>(a.x1[0], a.x2[2], a.Wb + (size_t) 2*262144, a.C[2],  a.part[2],  local, smem); break;
        case 1:  run_path<5,5,5,16,32, 4>(a.x1[2], a.x2[2], a.Wb + (size_t)10*262144, a.C[10], a.part[10], local, smem); break;
        case 2:  run_path<3,3,5,16,20, 4>(a.x1[1], a.x2[1], a.Wb + (size_t) 5*262144, a.C[5],  a.part[5],  local, smem); break;
        case 3:  run_path<5,1,5,16, 8,16>(a.x1[2], a.x2[0], a.Wb + (size_t) 7*262144, a.C[7],  a.part[7],  local, smem); break;
        case 4:  run_path<3,5,3,16,20, 8>(a.x1[1], a.x2[2], a.Wb + (size_t) 6*262144, a.C[6],  a.part[6],  local, smem); break;
        case 5:  run_path<1,3,3,32,12, 2>(a.x1[0], a.x2[1], a.Wb + (size_t) 1*262144, a.C[1],  a.part[1],  local, smem); break;
        case 6:  run_path<5,3,3,32,12, 2>(a.x1[2], a.x2[1], a.Wb + (size_t) 8*262144, a.C[8],  a.part[8],  local, smem); break;
        case 7:  run_path<3,1,3,32, 4, 8>(a.x1[1], a.x2[0], a.Wb + (size_t) 3*262144, a.C[3],  a.part[3],  local, smem); break;
        case 8:  run_path<5,5,1,32, 8, 8>(a.x1[2], a.x2[2], a.Wb + (size_t) 9*262144, a.C[9],  a.part[9],  local, smem); break;
        case 9:  run_path<3,3,1,32, 4,16>(a.x1[1], a.x2[1], a.Wb + (size_t) 4*262144, a.C[4],  a.part[4],  local, smem); break;
        case 10: run_path<1,1,1,32, 4,16>(a.x1[0], a.x2[0], a.Wb + (size_t) 0*262144, a.C[0],  a.part[0],  local, smem); break;
        default: break;
    }
}

// ---------------- reduce: sum partials into out[z][w][9] ----------------
// usub split across the 4 waves of a block (35 loads/thread, 16 waves/CU),
// LDS combine. Was: 140 loads/thread at 1 block/CU (latency-bound).

struct RArgs {
    const float* part[11];
    float*       out;
};

__global__ __launch_bounds__(NTHREADS) void reduce_out(RArgs r)
{
    __shared__ float red[3 * 64 * 9];
    const int lane = threadIdx.x & 63, us = threadIdx.x >> 6;
    const int zw = blockIdx.x * 64 + lane;      // z*64+w
    const int z = zw >> 6, w = zw & 63;

    float o[9];
#pragma unroll
    for (int i = 0; i < 9; ++i) o[i] = 0.f;

    {   // l3=0 (slot 0), paths {0,4,9}, K1=1
        const int P[3] = {0, 4, 9};
#pragma unroll
        for (int pi = 0; pi < 3; ++pi)
            o[0] += r.part[P[pi]][(size_t)(us * 1024 + z) * 64 + w];
    }
    {   // l3=1 (slots 1..3), paths {1,3,6,8}, K1=3
        const int P[4] = {1, 3, 6, 8};
#pragma unroll
        for (int pi = 0; pi < 4; ++pi) {
            const float* row = r.part[P[pi]] + ((size_t)(us * 1024 + z) * 64 + w) * 3;
#pragma unroll
            for (int k = 0; k < 3; ++k) o[1 + k] += row[k];
        }
    }
    {   // l3=2 (slots 4..8), paths {2,5,7,10}, K1=5
        const int P[4] = {2, 5, 7, 10};
#pragma unroll
        for (int pi = 0; pi < 4; ++pi) {
            const float* row = r.part[P[pi]] + ((size_t)(us * 1024 + z) * 64 + w) * 5;
#pragma unroll
            for (int k = 0; k < 5; ++k) o[4 + k] += row[k];
        }
    }

    if (us > 0) {
#pragma unroll
        for (int i = 0; i < 9; ++i) red[((us - 1) * 64 + lane) * 9 + i] = o[i];
    }
    __syncthreads();
    if (us == 0) {
#pragma unroll
        for (int i = 0; i < 9; ++i)
            o[i] += red[(0 * 64 + lane) * 9 + i]
                  + red[(1 * 64 + lane) * 9 + i]
                  + red[(2 * 64 + lane) * 9 + i];
        float* op = r.out + (size_t)zw * 9;
#pragma unroll
        for (int i = 0; i < 9; ++i) op[i] = o[i];
    }
}

// ---------------- launch ----------------

extern "C" void kernel_launch(void* const* d_in, const int* in_sizes, int n_in,
                              void* d_out, int out_size, void* d_ws, size_t ws_size,
                              hipStream_t stream)
{
    static const int cumK1[11] = {0, 1, 4, 9, 12, 13, 18, 21, 26, 29, 30}; // prefix of K1

    unsigned short* Wb = (unsigned short*)d_ws;                       // 5.77 MB
    float* partbase = (float*)((char*)d_ws + (6u << 20));             // 30.7 MB

    KArgs a;
    // dict order: x1_l0, x2_l0, x1_l1, x2_l1, x1_l2, x2_l2, W, C_0..C_10
    a.x1[0] = (const float*)d_in[0];
    a.x2[0] = (const float*)d_in[1];
    a.x1[1] = (const float*)d_in[2];
    a.x2[1] = (const float*)d_in[3];
    a.x1[2] = (const float*)d_in[4];
    a.x2[2] = (const float*)d_in[5];
    a.Wb = Wb;
    RArgs rr;
    for (int p = 0; p < 11; ++p) {
        a.C[p]    = (const float*)d_in[7 + p];
        a.part[p] = partbase + (size_t)cumK1[p] * 262144;   // 4*1024*64 per K1-slot
        rr.part[p] = a.part[p];
    }
    rr.out = (float*)d_out;

    prep_w<<<dim3(720896 / NTHREADS), NTHREADS, 0, stream>>>((const float*)d_in[6], Wb);
    tp_main<<<dim3(2048), NTHREADS, 0, stream>>>(a);
    reduce_out<<<dim3(1024), NTHREADS, 0, stream>>>(rr);
}

// Round 3
// 210.544 us; speedup vs baseline: 1.2068x; 1.2068x over previous
//
#include <hip/hip_runtime.h>

// HarmonicFullyConnectedTensorProduct, lmax=2, MUL=64, B=1024, 11 paths.
// out[z,w,k] += sum_{u,v,m,n} x1[z,u,m] x2[z,v,n] W[p,w,u,v] C_p[m,n,k]
//
// Round 11: R8 structure (183us total, tp_main 89us) + verified-safe R9 pieces.
// R10 post-mortem: per-thread element-map arrays spilled to scratch
// (FETCH 16.5->142.7 MB, WRITE 35.8->140.7 MB, VGPR 52->48) -> 1.8x slower.
// This round: inline slab decode (R8 form, no arrays), KEEP the verified
// KP-strided slab + v_pk_fma_f32 + v_cvt_pk_bf16_f32 tform (fewer VALU ops in
// the dominant phase), R8 UC values, SMEM 40192 (<=40960 -> 4 blocks/CU),
// launch_bounds(256,4). reduce_out 4-wave split + cvt_pk prep_w kept.

#define NTHREADS 256
#define SMEM_BYTES 40192

typedef __attribute__((ext_vector_type(4))) float f32x4;
typedef __attribute__((ext_vector_type(2))) float f32x2;
typedef __attribute__((ext_vector_type(8))) short s16x8;

// ---------------- prep: W fp32 [p][w][u][v] -> bf16 [p][u][w][v] ----------------

__global__ __launch_bounds__(NTHREADS) void prep_w(const float* __restrict__ W,
                                                   unsigned short* __restrict__ Wb)
{
    int id = blockIdx.x * NTHREADS + threadIdx.x;   // (p,u,w,v4): 11*64*64*16
    int v4 = (id & 15) << 2;
    int w  = (id >> 4) & 63;
    int u  = (id >> 10) & 63;
    int p  = id >> 16;
    float4 f = *(const float4*)(W + (((size_t)p * 64 + w) * 64 + u) * 64 + v4);
    unsigned r0, r1;
    asm("v_cvt_pk_bf16_f32 %0, %1, %2" : "=v"(r0) : "v"(f.x), "v"(f.y));
    asm("v_cvt_pk_bf16_f32 %0, %1, %2" : "=v"(r1) : "v"(f.z), "v"(f.w));
    union { unsigned u2[2]; ushort4 h; } pk;
    pk.u2[0] = r0; pk.u2[1] = r1;
    *(ushort4*)(Wb + (((size_t)p * 64 + u) * 64 + w) * 64 + v4) = pk.h;
}

// ---------------- main ----------------

struct KArgs {
    const float*          x1[3];
    const float*          x2[3];
    const unsigned short* Wb;
    const float*          C[11];
    float*                part[11];   // per-path partials [4 usub][1024][64][K1]
};

// S1 = pad4(N1*KP), KP = (K1==1)?1:K1+1  (even stride so k-pairs are 8B aligned)
template <int M1, int N1, int K1, int ZT, int S1, int UC>
__device__ __forceinline__ void run_path(const float* __restrict__ x1g,
                                         const float* __restrict__ x2g,
                                         const unsigned short* __restrict__ Wbp,
                                         const float* __restrict__ Cg,
                                         float* __restrict__ partp,
                                         int local, char* __restrict__ smem)
{
    constexpr int KP   = (K1 == 1) ? 1 : (K1 + 1);
    constexpr int KN   = K1 * N1;             // valid c1 elements per (z,u)
    constexpr int NC   = ZT * K1 / 16;        // MFMA col-tiles
    constexpr bool EVEN = (NC % 2 == 0);
    constexpr int ROWT = EVEN ? 2 : 1;        // w-tiles per wave
    constexpr int COLT = EVEN ? NC / 2 : NC;  // col-tiles per wave
    constexpr int NI   = ZT / 4;              // T-form z-iters
    constexpr int SST  = UC * S1 + 4;         // sc1 z-stride (floats)
    constexpr int TROWS = ZT * K1;
    constexpr int TOT  = ZT * UC * KN;

    float*          sC  = (float*)smem;                        // [<=125]
    float*          sc1 = (float*)(smem + 512);                // [ZT][SST]
    unsigned short* sT0 = (unsigned short*)(smem + 512 + ZT * SST * 4);
    // sT0: 2 buffers x TROWS x 72 bf16

    const int t = threadIdx.x, lane = t & 63, wave = t >> 6;
    const int ln = lane & 15, q = lane >> 4;
    const int ztile = local >> 2, usub = local & 3;
    const int z0 = ztile * ZT, u0 = usub * 16;

    for (int i = t; i < M1 * N1 * K1; i += NTHREADS) sC[i] = Cg[i];
    __syncthreads();

    // cooperative c1 slab build for u in [u0+us0, u0+us0+UC)
    // inline decode (constants -> magic-mul); NO per-thread map arrays (R10
    // spilled those to scratch: +210 MB HBM traffic).
    auto build_slab = [&](int us0) {
        for (int i = t; i < TOT; i += NTHREADS) {
            const int z   = i / (UC * KN);
            const int r_  = i - z * (UC * KN);
            const int uu2 = r_ / KN;
            const int j   = r_ - uu2 * KN;
            const int n   = j / K1;
            const int k   = j - n * K1;
            const float* x1r = x1g + ((size_t)(z0 + z) * 64 + u0 + us0 + uu2) * M1;
            float s = 0.f;
#pragma unroll
            for (int m = 0; m < M1; ++m) s += x1r[m] * sC[m * KN + n * K1 + k];
            sc1[z * SST + uu2 * S1 + n * KP + k] = s;
        }
    };

    // x2 for this thread's (z = i*4+wave, v = lane), reused across all u
    float xr[NI][N1];
#pragma unroll
    for (int i = 0; i < NI; ++i) {
        const float* xp = x2g + ((size_t)(z0 + i * 4 + wave) * 64 + lane) * N1;
#pragma unroll
        for (int n = 0; n < N1; ++n) xr[i][n] = xp[n];
    }

    // T-form for u-offset uf into buffer sTn (packed k-pair FMA + HW RNE cvt)
    auto tform = [&](int uf, unsigned short* sTn) {
        const int uus = uf & (UC - 1);
#pragma unroll
        for (int i = 0; i < NI; ++i) {
            const int z = i * 4 + wave;                 // wave-uniform
            const float* cp = &sc1[z * SST + uus * S1]; // broadcast reads
            float c1v[S1];
#pragma unroll
            for (int jj = 0; jj < S1 / 4; ++jj) {
                float4 f = ((const float4*)cp)[jj];
                c1v[jj * 4 + 0] = f.x; c1v[jj * 4 + 1] = f.y;
                c1v[jj * 4 + 2] = f.z; c1v[jj * 4 + 3] = f.w;
            }
            unsigned short* dst = sTn + lane;
            if constexpr (K1 == 1) {
                float s = 0.f;
#pragma unroll
                for (int n = 0; n < N1; ++n) s += xr[i][n] * c1v[n];
                unsigned rr; const float zz = 0.f;
                asm("v_cvt_pk_bf16_f32 %0, %1, %2" : "=v"(rr) : "v"(s), "v"(zz));
                dst[z * 72] = (unsigned short)rr;
            } else {
                constexpr int NPAIR = K1 / 2;           // K1 is odd: 5->2, 3->1
                f32x2 acc2[NPAIR];
                float accl = 0.f;
#pragma unroll
                for (int p2 = 0; p2 < NPAIR; ++p2) acc2[p2] = (f32x2){0.f, 0.f};
#pragma unroll
                for (int n = 0; n < N1; ++n) {
                    const float xv = xr[i][n];
                    const f32x2 bb = (f32x2){xv, xv};
#pragma unroll
                    for (int p2 = 0; p2 < NPAIR; ++p2) {
                        const f32x2 cc = (f32x2){c1v[n * KP + 2 * p2],
                                                 c1v[n * KP + 2 * p2 + 1]};
                        acc2[p2] = __builtin_elementwise_fma(bb, cc, acc2[p2]);
                    }
                    accl += xv * c1v[n * KP + K1 - 1];  // odd trailing k
                }
#pragma unroll
                for (int p2 = 0; p2 < NPAIR; ++p2) {
                    unsigned rr;
                    asm("v_cvt_pk_bf16_f32 %0, %1, %2"
                        : "=v"(rr) : "v"(acc2[p2].x), "v"(acc2[p2].y));
                    dst[(z * K1 + 2 * p2) * 72]     = (unsigned short)rr;
                    dst[(z * K1 + 2 * p2 + 1) * 72] = (unsigned short)(rr >> 16);
                }
                {
                    unsigned rr; const float zz = 0.f;
                    asm("v_cvt_pk_bf16_f32 %0, %1, %2"
                        : "=v"(rr) : "v"(accl), "v"(zz));
                    dst[(z * K1 + K1 - 1) * 72] = (unsigned short)rr;
                }
            }
        }
    };

    f32x4 acc[ROWT][COLT];
#pragma unroll
    for (int rt = 0; rt < ROWT; ++rt)
#pragma unroll
        for (int ci = 0; ci < COLT; ++ci) acc[rt][ci] = (f32x4){0.f, 0.f, 0.f, 0.f};

    build_slab(0);
    __syncthreads();
    tform(0, sT0);
    __syncthreads();

#pragma unroll 2
    for (int uu = 0; uu < 16; ++uu) {
        if (((uu + 1) & (UC - 1)) == 0 && (uu + 1) < 16) {
            // refill sc1 for next slab; prior readers finished before last barrier
            build_slab(uu + 1);
            __syncthreads();
        }
        const int cur = uu & 1;
        unsigned short* sTc = sT0 + cur * (TROWS * 72);
        unsigned short* sTn = sT0 + (cur ^ 1) * (TROWS * 72);

        // A-frags for THIS u straight from L2 (issued early = in-iter prefetch)
        const unsigned short* wsrc = Wbp + (size_t)(u0 + uu) * 4096;
        s16x8 areg[ROWT][2];
#pragma unroll
        for (int rt = 0; rt < ROWT; ++rt) {
            const int wt = EVEN ? ((wave >> 1) * 2 + rt) : wave;
#pragma unroll
            for (int s2 = 0; s2 < 2; ++s2)
                areg[rt][s2] = *(const s16x8*)(wsrc + (wt * 16 + ln) * 64 + s2 * 32 + q * 8);
        }

        // T-form next u (writes sTn) — overlaps with MFMA below in the pipes
        if (uu < 15) tform(uu + 1, sTn);

        // MFMA from sTc
#pragma unroll
        for (int ci = 0; ci < COLT; ++ci) {
            const int c = EVEN ? ((wave & 1) * COLT + ci) : ci;
            s16x8 bf0 = *(const s16x8*)&sTc[(c * 16 + ln) * 72 + q * 8];
            s16x8 bf1 = *(const s16x8*)&sTc[(c * 16 + ln) * 72 + 32 + q * 8];
#pragma unroll
            for (int rt = 0; rt < ROWT; ++rt) {
                acc[rt][ci] = __builtin_amdgcn_mfma_f32_16x16x32_bf16(
                    areg[rt][0], bf0, acc[rt][ci], 0, 0, 0);
                acc[rt][ci] = __builtin_amdgcn_mfma_f32_16x16x32_bf16(
                    areg[rt][1], bf1, acc[rt][ci], 0, 0, 0);
            }
        }
        __syncthreads();
    }

    // ---- epilogue: plain stores to per-(path,usub) partials (no atomics)
#pragma unroll
    for (int rt = 0; rt < ROWT; ++rt) {
        const int wt = EVEN ? ((wave >> 1) * 2 + rt) : wave;
#pragma unroll
        for (int ci = 0; ci < COLT; ++ci) {
            const int c = EVEN ? ((wave & 1) * COLT + ci) : ci;
            const int col = c * 16 + ln;
            const int z = col / K1, k = col - z * K1;
            float* op = partp + ((size_t)(usub * 1024 + z0 + z) * 64) * K1 + k;
#pragma unroll
            for (int r = 0; r < 4; ++r)
                op[(wt * 16 + q * 4 + r) * K1] = acc[rt][ci][r];
        }
    }
}

__global__ __launch_bounds__(NTHREADS, 4) void tp_main(KArgs a)
{
    __shared__ __align__(16) char smem[SMEM_BYTES];

    const int bid = blockIdx.x;
    // heavy-first: p2,p10,p5,p7,p6 (256 ea, ZT16), then p1,p8,p3,p9,p4,p0 (128 ea, ZT32)
    const int starts[12] = {0, 256, 512, 768, 1024, 1280, 1408, 1536, 1664, 1792, 1920, 2048};
    int idx = 0;
#pragma unroll
    for (int i = 1; i < 12; ++i) idx += (bid >= starts[i]) ? 1 : 0;
    const int local = bid - starts[idx];

    switch (idx) {            //  M1 N1 K1 ZT S1 UC    (S1 = pad4(N1*KP))
        case 0:  run_path<1,5,5,16,32, 8>(a.x1[0], a.x2[2], a.Wb + (size_t) 2*262144, a.C[2],  a.part[2],  local, smem); break;
        case 1:  run_path<5,5,5,16,32, 8>(a.x1[2], a.x2[2], a.Wb + (size_t)10*262144, a.C[10], a.part[10], local, smem); break;
        case 2:  run_path<3,3,5,16,20, 8>(a.x1[1], a.x2[1], a.Wb + (size_t) 5*262144, a.C[5],  a.part[5],  local, smem); break;
        case 3:  run_path<5,1,5,16, 8,16>(a.x1[2], a.x2[0], a.Wb + (size_t) 7*262144, a.C[7],  a.part[7],  local, smem); break;
        case 4:  run_path<3,5,3,16,20, 8>(a.x1[1], a.x2[2], a.Wb + (size_t) 6*262144, a.C[6],  a.part[6],  local, smem); break;
        case 5:  run_path<1,3,3,32,12, 4>(a.x1[0], a.x2[1], a.Wb + (size_t) 1*262144, a.C[1],  a.part[1],  local, smem); break;
        case 6:  run_path<5,3,3,32,12, 4>(a.x1[2], a.x2[1], a.Wb + (size_t) 8*262144, a.C[8],  a.part[8],  local, smem); break;
        case 7:  run_path<3,1,3,32, 4,16>(a.x1[1], a.x2[0], a.Wb + (size_t) 3*262144, a.C[3],  a.part[3],  local, smem); break;
        case 8:  run_path<5,5,1,32, 8,16>(a.x1[2], a.x2[2], a.Wb + (size_t) 9*262144, a.C[9],  a.part[9],  local, smem); break;
        case 9:  run_path<3,3,1,32, 4,16>(a.x1[1], a.x2[1], a.Wb + (size_t) 4*262144, a.C[4],  a.part[4],  local, smem); break;
        case 10: run_path<1,1,1,32, 4,16>(a.x1[0], a.x2[0], a.Wb + (size_t) 0*262144, a.C[0],  a.part[0],  local, smem); break;
        default: break;
    }
}

// ---------------- reduce: sum partials into out[z][w][9] ----------------
// usub split across the 4 waves of a block (35 loads/thread, 16 waves/CU),
// LDS combine.

struct RArgs {
    const float* part[11];
    float*       out;
};

__global__ __launch_bounds__(NTHREADS) void reduce_out(RArgs r)
{
    __shared__ float red[3 * 64 * 9];
    const int lane = threadIdx.x & 63, us = threadIdx.x >> 6;
    const int zw = blockIdx.x * 64 + lane;      // z*64+w
    const int z = zw >> 6, w = zw & 63;

    float o[9];
#pragma unroll
    for (int i = 0; i < 9; ++i) o[i] = 0.f;

    {   // l3=0 (slot 0), paths {0,4,9}, K1=1
        const int P[3] = {0, 4, 9};
#pragma unroll
        for (int pi = 0; pi < 3; ++pi)
            o[0] += r.part[P[pi]][(size_t)(us * 1024 + z) * 64 + w];
    }
    {   // l3=1 (slots 1..3), paths {1,3,6,8}, K1=3
        const int P[4] = {1, 3, 6, 8};
#pragma unroll
        for (int pi = 0; pi < 4; ++pi) {
            const float* row = r.part[P[pi]] + ((size_t)(us * 1024 + z) * 64 + w) * 3;
#pragma unroll
            for (int k = 0; k < 3; ++k) o[1 + k] += row[k];
        }
    }
    {   // l3=2 (slots 4..8), paths {2,5,7,10}, K1=5
        const int P[4] = {2, 5, 7, 10};
#pragma unroll
        for (int pi = 0; pi < 4; ++pi) {
            const float* row = r.part[P[pi]] + ((size_t)(us * 1024 + z) * 64 + w) * 5;
#pragma unroll
            for (int k = 0; k < 5; ++k) o[4 + k] += row[k];
        }
    }

    if (us > 0) {
#pragma unroll
        for (int i = 0; i < 9; ++i) red[((us - 1) * 64 + lane) * 9 + i] = o[i];
    }
    __syncthreads();
    if (us == 0) {
#pragma unroll
        for (int i = 0; i < 9; ++i)
            o[i] += red[(0 * 64 + lane) * 9 + i]
                  + red[(1 * 64 + lane) * 9 + i]
                  + red[(2 * 64 + lane) * 9 + i];
        float* op = r.out + (size_t)zw * 9;
#pragma unroll
        for (int i = 0; i < 9; ++i) op[i] = o[i];
    }
}

// ---------------- launch ----------------

extern "C" void kernel_launch(void* const* d_in, const int* in_sizes, int n_in,
                              void* d_out, int out_size, void* d_ws, size_t ws_size,
                              hipStream_t stream)
{
    static const int cumK1[11] = {0, 1, 4, 9, 12, 13, 18, 21, 26, 29, 30}; // prefix of K1

    unsigned short* Wb = (unsigned short*)d_ws;                       // 5.77 MB
    float* partbase = (float*)((char*)d_ws + (6u << 20));             // 30.7 MB

    KArgs a;
    // dict order: x1_l0, x2_l0, x1_l1, x2_l1, x1_l2, x2_l2, W, C_0..C_10
    a.x1[0] = (const float*)d_in[0];
    a.x2[0] = (const float*)d_in[1];
    a.x1[1] = (const float*)d_in[2];
    a.x2[1] = (const float*)d_in[3];
    a.x1[2] = (const float*)d_in[4];
    a.x2[2] = (const float*)d_in[5];
    a.Wb = Wb;
    RArgs rr;
    for (int p = 0; p < 11; ++p) {
        a.C[p]    = (const float*)d_in[7 + p];
        a.part[p] = partbase + (size_t)cumK1[p] * 262144;   // 4*1024*64 per K1-slot
        rr.part[p] = a.part[p];
    }
    rr.out = (float*)d_out;

    prep_w<<<dim3(720896 / NTHREADS), NTHREADS, 0, stream>>>((const float*)d_in[6], Wb);
    tp_main<<<dim3(2048), NTHREADS, 0, stream>>>(a);
    reduce_out<<<dim3(1024), NTHREADS, 0, stream>>>(rr);
}

// Round 4
// 180.742 us; speedup vs baseline: 1.4058x; 1.1649x over previous
//
#include <hip/hip_runtime.h>

// HarmonicFullyConnectedTensorProduct, lmax=2, MUL=64, B=1024, 11 paths.
// out[z,w,k] += sum_{u,v,m,n} x1[z,u,m] x2[z,v,n] W[p,w,u,v] C_p[m,n,k]
//
// Round 12: R8's exact tp_main (proven 89us) with ONE change: float->bf16
// conversion via native __bf16 fptrunc (lowers to HW v_cvt_pk_bf16_f32 on
// gfx950; RNE; 1 op; no inline asm). R10/R11 post-mortem: element-map arrays
// and per-pair inline-asm cvt_pk both caused scratch spill (WRITE_SIZE
// 35.8 -> 140.7 / 44.3 MB) — reverted. Keep 4-wave reduce_out.

#define NTHREADS 256
#define SMEM_BYTES 38144

typedef __attribute__((ext_vector_type(4))) float f32x4;
typedef __attribute__((ext_vector_type(8))) short s16x8;

__device__ __forceinline__ unsigned short f2bf(float x) {
    // native fptrunc float->bfloat: RNE, lowered by the backend (v_cvt_pk_bf16_f32
    // on gfx950). No manual bit-twiddle, no asm — compiler schedules/pairs it.
    __bf16 b = (__bf16)x;
    union { __bf16 h; unsigned short u; } v;
    v.h = b;
    return v.u;
}

// ---------------- prep: W fp32 [p][w][u][v] -> bf16 [p][u][w][v] ----------------

__global__ __launch_bounds__(NTHREADS) void prep_w(const float* __restrict__ W,
                                                   unsigned short* __restrict__ Wb)
{
    int id = blockIdx.x * NTHREADS + threadIdx.x;   // (p,u,w,v4): 11*64*64*16
    int v4 = (id & 15) << 2;
    int w  = (id >> 4) & 63;
    int u  = (id >> 10) & 63;
    int p  = id >> 16;
    float4 f = *(const float4*)(W + (((size_t)p * 64 + w) * 64 + u) * 64 + v4);
    ushort4 h;
    h.x = f2bf(f.x); h.y = f2bf(f.y); h.z = f2bf(f.z); h.w = f2bf(f.w);
    *(ushort4*)(Wb + (((size_t)p * 64 + u) * 64 + w) * 64 + v4) = h;
}

// ---------------- main ----------------

struct KArgs {
    const float*          x1[3];
    const float*          x2[3];
    const unsigned short* Wb;
    const float*          C[11];
    float*                part[11];   // per-path partials [4 usub][1024][64][K1]
};

template <int M1, int N1, int K1, int ZT, int S1, int UC>
__device__ __forceinline__ void run_path(const float* __restrict__ x1g,
                                         const float* __restrict__ x2g,
                                         const unsigned short* __restrict__ Wbp,
                                         const float* __restrict__ Cg,
                                         float* __restrict__ partp,
                                         int local, char* __restrict__ smem)
{
    constexpr int KN   = K1 * N1;
    constexpr int NC   = ZT * K1 / 16;        // MFMA col-tiles
    constexpr bool EVEN = (NC % 2 == 0);
    constexpr int ROWT = EVEN ? 2 : 1;        // w-tiles per wave
    constexpr int COLT = EVEN ? NC / 2 : NC;  // col-tiles per wave
    constexpr int NI   = ZT / 4;              // T-form z-iters
    constexpr int SST  = UC * S1 + 4;         // sc1 z-stride (floats)
    constexpr int TROWS = ZT * K1;

    float*          sC  = (float*)smem;                        // [<=125]
    float*          sc1 = (float*)(smem + 512);                // [ZT][SST]
    unsigned short* sT0 = (unsigned short*)(smem + 512 + ZT * SST * 4);
    // sT0: 2 buffers x TROWS x 72 bf16

    const int t = threadIdx.x, lane = t & 63, wave = t >> 6;
    const int ln = lane & 15, q = lane >> 4;
    const int ztile = local >> 2, usub = local & 3;
    const int z0 = ztile * ZT, u0 = usub * 16;

    for (int i = t; i < M1 * N1 * K1; i += NTHREADS) sC[i] = Cg[i];
    __syncthreads();

    // cooperative c1 slab build: sc1[z][uu2*S1 + k*N1+n] for u in [u0+us0, +UC)
    auto build_slab = [&](int us0) {
        for (int i = t; i < ZT * UC * KN; i += NTHREADS) {
            int z   = i / (UC * KN);
            int r   = i - z * (UC * KN);
            int uu2 = r / KN;
            int j   = r - uu2 * KN;
            int k   = j / N1, n = j - k * N1;
            const float* x1r = x1g + ((size_t)(z0 + z) * 64 + u0 + us0 + uu2) * M1;
            float s = 0.f;
#pragma unroll
            for (int m = 0; m < M1; ++m) s += x1r[m] * sC[(m * N1 + n) * K1 + k];
            sc1[z * SST + uu2 * S1 + j] = s;
        }
    };

    // x2 for this thread's (z = i*4+wave, v = lane), reused across all u
    float xr[NI][N1];
#pragma unroll
    for (int i = 0; i < NI; ++i) {
        const float* xp = x2g + ((size_t)(z0 + i * 4 + wave) * 64 + lane) * N1;
#pragma unroll
        for (int n = 0; n < N1; ++n) xr[i][n] = xp[n];
    }

    // T-form for u-offset uf into buffer sTn
    auto tform = [&](int uf, unsigned short* sTn) {
        const int uus = uf & (UC - 1);
#pragma unroll
        for (int i = 0; i < NI; ++i) {
            const int z = i * 4 + wave;                 // wave-uniform
            const float4* cp = (const float4*)&sc1[z * SST + uus * S1];
            float c1v[S1];
#pragma unroll
            for (int jj = 0; jj < S1 / 4; ++jj) {
                float4 f = cp[jj];
                c1v[jj * 4 + 0] = f.x; c1v[jj * 4 + 1] = f.y;
                c1v[jj * 4 + 2] = f.z; c1v[jj * 4 + 3] = f.w;
            }
#pragma unroll
            for (int k = 0; k < K1; ++k) {
                float s = 0.f;
#pragma unroll
                for (int n = 0; n < N1; ++n) s += xr[i][n] * c1v[k * N1 + n];
                sTn[(z * K1 + k) * 72 + lane] = f2bf(s);
            }
        }
    };

    f32x4 acc[ROWT][COLT];
#pragma unroll
    for (int rt = 0; rt < ROWT; ++rt)
#pragma unroll
        for (int ci = 0; ci < COLT; ++ci) acc[rt][ci] = (f32x4){0.f, 0.f, 0.f, 0.f};

    build_slab(0);
    __syncthreads();
    tform(0, sT0);
    __syncthreads();

#pragma unroll 2
    for (int uu = 0; uu < 16; ++uu) {
        if (((uu + 1) & (UC - 1)) == 0 && (uu + 1) < 16) {
            // refill sc1 for next slab; prior readers finished before last barrier
            build_slab(uu + 1);
            __syncthreads();
        }
        const int cur = uu & 1;
        unsigned short* sTc = sT0 + cur * (TROWS * 72);
        unsigned short* sTn = sT0 + (cur ^ 1) * (TROWS * 72);

        // A-frags for THIS u straight from L2 (issued early = in-iter prefetch)
        const unsigned short* wsrc = Wbp + (size_t)(u0 + uu) * 4096;
        s16x8 areg[ROWT][2];
#pragma unroll
        for (int rt = 0; rt < ROWT; ++rt) {
            const int wt = EVEN ? ((wave >> 1) * 2 + rt) : wave;
#pragma unroll
            for (int s2 = 0; s2 < 2; ++s2)
                areg[rt][s2] = *(const s16x8*)(wsrc + (wt * 16 + ln) * 64 + s2 * 32 + q * 8);
        }

        // T-form next u (writes sTn) — overlaps with MFMA below in the pipes
        if (uu < 15) tform(uu + 1, sTn);

        // MFMA from sTc
#pragma unroll
        for (int ci = 0; ci < COLT; ++ci) {
            const int c = EVEN ? ((wave & 1) * COLT + ci) : ci;
            s16x8 bf0 = *(const s16x8*)&sTc[(c * 16 + ln) * 72 + q * 8];
            s16x8 bf1 = *(const s16x8*)&sTc[(c * 16 + ln) * 72 + 32 + q * 8];
#pragma unroll
            for (int rt = 0; rt < ROWT; ++rt) {
                acc[rt][ci] = __builtin_amdgcn_mfma_f32_16x16x32_bf16(
                    areg[rt][0], bf0, acc[rt][ci], 0, 0, 0);
                acc[rt][ci] = __builtin_amdgcn_mfma_f32_16x16x32_bf16(
                    areg[rt][1], bf1, acc[rt][ci], 0, 0, 0);
            }
        }
        __syncthreads();
    }

    // ---- epilogue: plain stores to per-(path,usub) partials (no atomics)
#pragma unroll
    for (int rt = 0; rt < ROWT; ++rt) {
        const int wt = EVEN ? ((wave >> 1) * 2 + rt) : wave;
#pragma unroll
        for (int ci = 0; ci < COLT; ++ci) {
            const int c = EVEN ? ((wave & 1) * COLT + ci) : ci;
            const int col = c * 16 + ln;
            const int z = col / K1, k = col - z * K1;
            float* op = partp + ((size_t)(usub * 1024 + z0 + z) * 64) * K1 + k;
#pragma unroll
            for (int r = 0; r < 4; ++r)
                op[(wt * 16 + q * 4 + r) * K1] = acc[rt][ci][r];
        }
    }
}

__global__ __launch_bounds__(NTHREADS, 4) void tp_main(KArgs a)
{
    __shared__ __align__(16) char smem[SMEM_BYTES];

    const int bid = blockIdx.x;
    // heavy-first: p2,p10,p5,p7,p6 (256 ea, ZT16), then p1,p8,p3,p9,p4,p0 (128 ea, ZT32)
    const int starts[12] = {0, 256, 512, 768, 1024, 1280, 1408, 1536, 1664, 1792, 1920, 2048};
    int idx = 0;
#pragma unroll
    for (int i = 1; i < 12; ++i) idx += (bid >= starts[i]) ? 1 : 0;
    const int local = bid - starts[idx];

    switch (idx) {            //  M1 N1 K1 ZT S1 UC
        case 0:  run_path<1,5,5,16,28, 8>(a.x1[0], a.x2[2], a.Wb + (size_t) 2*262144, a.C[2],  a.part[2],  local, smem); break;
        case 1:  run_path<5,5,5,16,28, 8>(a.x1[2], a.x2[2], a.Wb + (size_t)10*262144, a.C[10], a.part[10], local, smem); break;
        case 2:  run_path<3,3,5,16,16, 8>(a.x1[1], a.x2[1], a.Wb + (size_t) 5*262144, a.C[5],  a.part[5],  local, smem); break;
        case 3:  run_path<5,1,5,16, 8,16>(a.x1[2], a.x2[0], a.Wb + (size_t) 7*262144, a.C[7],  a.part[7],  local, smem); break;
        case 4:  run_path<3,5,3,16,16, 8>(a.x1[1], a.x2[2], a.Wb + (size_t) 6*262144, a.C[6],  a.part[6],  local, smem); break;
        case 5:  run_path<1,3,3,32,12, 4>(a.x1[0], a.x2[1], a.Wb + (size_t) 1*262144, a.C[1],  a.part[1],  local, smem); break;
        case 6:  run_path<5,3,3,32,12, 4>(a.x1[2], a.x2[1], a.Wb + (size_t) 8*262144, a.C[8],  a.part[8],  local, smem); break;
        case 7:  run_path<3,1,3,32, 4,16>(a.x1[1], a.x2[0], a.Wb + (size_t) 3*262144, a.C[3],  a.part[3],  local, smem); break;
        case 8:  run_path<5,5,1,32, 8,16>(a.x1[2], a.x2[2], a.Wb + (size_t) 9*262144, a.C[9],  a.part[9],  local, smem); break;
        case 9:  run_path<3,3,1,32, 4,16>(a.x1[1], a.x2[1], a.Wb + (size_t) 4*262144, a.C[4],  a.part[4],  local, smem); break;
        case 10: run_path<1,1,1,32, 4,16>(a.x1[0], a.x2[0], a.Wb + (size_t) 0*262144, a.C[0],  a.part[0],  local, smem); break;
        default: break;
    }
}

// ---------------- reduce: sum partials into out[z][w][9] ----------------
// usub split across the 4 waves of a block (35 loads/thread, 16 waves/CU),
// LDS combine.

struct RArgs {
    const float* part[11];
    float*       out;
};

__global__ __launch_bounds__(NTHREADS) void reduce_out(RArgs r)
{
    __shared__ float red[3 * 64 * 9];
    const int lane = threadIdx.x & 63, us = threadIdx.x >> 6;
    const int zw = blockIdx.x * 64 + lane;      // z*64+w
    const int z = zw >> 6, w = zw & 63;

    float o[9];
#pragma unroll
    for (int i = 0; i < 9; ++i) o[i] = 0.f;

    {   // l3=0 (slot 0), paths {0,4,9}, K1=1
        const int P[3] = {0, 4, 9};
#pragma unroll
        for (int pi = 0; pi < 3; ++pi)
            o[0] += r.part[P[pi]][(size_t)(us * 1024 + z) * 64 + w];
    }
    {   // l3=1 (slots 1..3), paths {1,3,6,8}, K1=3
        const int P[4] = {1, 3, 6, 8};
#pragma unroll
        for (int pi = 0; pi < 4; ++pi) {
            const float* row = r.part[P[pi]] + ((size_t)(us * 1024 + z) * 64 + w) * 3;
#pragma unroll
            for (int k = 0; k < 3; ++k) o[1 + k] += row[k];
        }
    }
    {   // l3=2 (slots 4..8), paths {2,5,7,10}, K1=5
        const int P[4] = {2, 5, 7, 10};
#pragma unroll
        for (int pi = 0; pi < 4; ++pi) {
            const float* row = r.part[P[pi]] + ((size_t)(us * 1024 + z) * 64 + w) * 5;
#pragma unroll
            for (int k = 0; k < 5; ++k) o[4 + k] += row[k];
        }
    }

    if (us > 0) {
#pragma unroll
        for (int i = 0; i < 9; ++i) red[((us - 1) * 64 + lane) * 9 + i] = o[i];
    }
    __syncthreads();
    if (us == 0) {
#pragma unroll
        for (int i = 0; i < 9; ++i)
            o[i] += red[(0 * 64 + lane) * 9 + i]
                  + red[(1 * 64 + lane) * 9 + i]
                  + red[(2 * 64 + lane) * 9 + i];
        float* op = r.out + (size_t)zw * 9;
#pragma unroll
        for (int i = 0; i < 9; ++i) op[i] = o[i];
    }
}

// ---------------- launch ----------------

extern "C" void kernel_launch(void* const* d_in, const int* in_sizes, int n_in,
                              void* d_out, int out_size, void* d_ws, size_t ws_size,
                              hipStream_t stream)
{
    static const int cumK1[11] = {0, 1, 4, 9, 12, 13, 18, 21, 26, 29, 30}; // prefix of K1

    unsigned short* Wb = (unsigned short*)d_ws;                       // 5.77 MB
    float* partbase = (float*)((char*)d_ws + (6u << 20));             // 30.7 MB

    KArgs a;
    // dict order: x1_l0, x2_l0, x1_l1, x2_l1, x1_l2, x2_l2, W, C_0..C_10
    a.x1[0] = (const float*)d_in[0];
    a.x2[0] = (const float*)d_in[1];
    a.x1[1] = (const float*)d_in[2];
    a.x2[1] = (const float*)d_in[3];
    a.x1[2] = (const float*)d_in[4];
    a.x2[2] = (const float*)d_in[5];
    a.Wb = Wb;
    RArgs rr;
    for (int p = 0; p < 11; ++p) {
        a.C[p]    = (const float*)d_in[7 + p];
        a.part[p] = partbase + (size_t)cumK1[p] * 262144;   // 4*1024*64 per K1-slot
        rr.part[p] = a.part[p];
    }
    rr.out = (float*)d_out;

    prep_w<<<dim3(720896 / NTHREADS), NTHREADS, 0, stream>>>((const float*)d_in[6], Wb);
    tp_main<<<dim3(2048), NTHREADS, 0, stream>>>(a);
    reduce_out<<<dim3(1024), NTHREADS, 0, stream>>>(rr);
}

// Round 5
// 174.551 us; speedup vs baseline: 1.4556x; 1.0355x over previous
//
#include <hip/hip_runtime.h>

// HarmonicFullyConnectedTensorProduct, lmax=2, MUL=64, B=1024, 11 paths.
// out[z,w,k] += sum_{u,v,m,n} x1[z,u,m] x2[z,v,n] W[p,w,u,v] C_p[m,n,k]
//
// Round 13 (from R12: total 180.7us, tp_main 94us @ VALU 30% / MFMA 8% / occ 35%
// -> latency/stall-bound, both pipes idle; non-tp_main time ~86us):
//  1. Occupancy 4->5 blocks/CU: UC retuned (cases 0,1: 8->4; 5,6: 4->2; 7: 16->8)
//     so all paths fit LDS <= 32768; launch_bounds(256,5). Compute code untouched.
//  2. Partials transposed to [us][k][z][w]: epilogue = contiguous float4 stores
//     (w fast axis), reduce_out loads perfectly lane-coalesced (w = lane) ->
//     reduce goes scatter-latency-bound -> BW-bound.

#define NTHREADS 256
#define SMEM_BYTES 32768

typedef __attribute__((ext_vector_type(4))) float f32x4;
typedef __attribute__((ext_vector_type(8))) short s16x8;

__device__ __forceinline__ unsigned short f2bf(float x) {
    __bf16 b = (__bf16)x;
    union { __bf16 h; unsigned short u; } v;
    v.h = b;
    return v.u;
}

// ---------------- prep: W fp32 [p][w][u][v] -> bf16 [p][u][w][v] ----------------

__global__ __launch_bounds__(NTHREADS) void prep_w(const float* __restrict__ W,
                                                   unsigned short* __restrict__ Wb)
{
    int id = blockIdx.x * NTHREADS + threadIdx.x;   // (p,u,w,v4): 11*64*64*16
    int v4 = (id & 15) << 2;
    int w  = (id >> 4) & 63;
    int u  = (id >> 10) & 63;
    int p  = id >> 16;
    float4 f = *(const float4*)(W + (((size_t)p * 64 + w) * 64 + u) * 64 + v4);
    ushort4 h;
    h.x = f2bf(f.x); h.y = f2bf(f.y); h.z = f2bf(f.z); h.w = f2bf(f.w);
    *(ushort4*)(Wb + (((size_t)p * 64 + u) * 64 + w) * 64 + v4) = h;
}

// ---------------- main ----------------

struct KArgs {
    const float*          x1[3];
    const float*          x2[3];
    const unsigned short* Wb;
    const float*          C[11];
    float*                part[11];   // per-path partials [4 usub][K1][1024][64]
};

template <int M1, int N1, int K1, int ZT, int S1, int UC>
__device__ __forceinline__ void run_path(const float* __restrict__ x1g,
                                         const float* __restrict__ x2g,
                                         const unsigned short* __restrict__ Wbp,
                                         const float* __restrict__ Cg,
                                         float* __restrict__ partp,
                                         int local, char* __restrict__ smem)
{
    constexpr int KN   = K1 * N1;
    constexpr int NC   = ZT * K1 / 16;        // MFMA col-tiles
    constexpr bool EVEN = (NC % 2 == 0);
    constexpr int ROWT = EVEN ? 2 : 1;        // w-tiles per wave
    constexpr int COLT = EVEN ? NC / 2 : NC;  // col-tiles per wave
    constexpr int NI   = ZT / 4;              // T-form z-iters
    constexpr int SST  = UC * S1 + 4;         // sc1 z-stride (floats)
    constexpr int TROWS = ZT * K1;

    float*          sC  = (float*)smem;                        // [<=125]
    float*          sc1 = (float*)(smem + 512);                // [ZT][SST]
    unsigned short* sT0 = (unsigned short*)(smem + 512 + ZT * SST * 4);
    // sT0: 2 buffers x TROWS x 72 bf16

    const int t = threadIdx.x, lane = t & 63, wave = t >> 6;
    const int ln = lane & 15, q = lane >> 4;
    const int ztile = local >> 2, usub = local & 3;
    const int z0 = ztile * ZT, u0 = usub * 16;

    for (int i = t; i < M1 * N1 * K1; i += NTHREADS) sC[i] = Cg[i];
    __syncthreads();

    // cooperative c1 slab build: sc1[z][uu2*S1 + k*N1+n] for u in [u0+us0, +UC)
    auto build_slab = [&](int us0) {
        for (int i = t; i < ZT * UC * KN; i += NTHREADS) {
            int z   = i / (UC * KN);
            int r   = i - z * (UC * KN);
            int uu2 = r / KN;
            int j   = r - uu2 * KN;
            int k   = j / N1, n = j - k * N1;
            const float* x1r = x1g + ((size_t)(z0 + z) * 64 + u0 + us0 + uu2) * M1;
            float s = 0.f;
#pragma unroll
            for (int m = 0; m < M1; ++m) s += x1r[m] * sC[(m * N1 + n) * K1 + k];
            sc1[z * SST + uu2 * S1 + j] = s;
        }
    };

    // x2 for this thread's (z = i*4+wave, v = lane), reused across all u
    float xr[NI][N1];
#pragma unroll
    for (int i = 0; i < NI; ++i) {
        const float* xp = x2g + ((size_t)(z0 + i * 4 + wave) * 64 + lane) * N1;
#pragma unroll
        for (int n = 0; n < N1; ++n) xr[i][n] = xp[n];
    }

    // T-form for u-offset uf into buffer sTn
    auto tform = [&](int uf, unsigned short* sTn) {
        const int uus = uf & (UC - 1);
#pragma unroll
        for (int i = 0; i < NI; ++i) {
            const int z = i * 4 + wave;                 // wave-uniform
            const float4* cp = (const float4*)&sc1[z * SST + uus * S1];
            float c1v[S1];
#pragma unroll
            for (int jj = 0; jj < S1 / 4; ++jj) {
                float4 f = cp[jj];
                c1v[jj * 4 + 0] = f.x; c1v[jj * 4 + 1] = f.y;
                c1v[jj * 4 + 2] = f.z; c1v[jj * 4 + 3] = f.w;
            }
#pragma unroll
            for (int k = 0; k < K1; ++k) {
                float s = 0.f;
#pragma unroll
                for (int n = 0; n < N1; ++n) s += xr[i][n] * c1v[k * N1 + n];
                sTn[(z * K1 + k) * 72 + lane] = f2bf(s);
            }
        }
    };

    f32x4 acc[ROWT][COLT];
#pragma unroll
    for (int rt = 0; rt < ROWT; ++rt)
#pragma unroll
        for (int ci = 0; ci < COLT; ++ci) acc[rt][ci] = (f32x4){0.f, 0.f, 0.f, 0.f};

    build_slab(0);
    __syncthreads();
    tform(0, sT0);
    __syncthreads();

#pragma unroll 2
    for (int uu = 0; uu < 16; ++uu) {
        if (((uu + 1) & (UC - 1)) == 0 && (uu + 1) < 16) {
            // refill sc1 for next slab; prior readers finished before last barrier
            build_slab(uu + 1);
            __syncthreads();
        }
        const int cur = uu & 1;
        unsigned short* sTc = sT0 + cur * (TROWS * 72);
        unsigned short* sTn = sT0 + (cur ^ 1) * (TROWS * 72);

        // A-frags for THIS u straight from L2 (issued early = in-iter prefetch)
        const unsigned short* wsrc = Wbp + (size_t)(u0 + uu) * 4096;
        s16x8 areg[ROWT][2];
#pragma unroll
        for (int rt = 0; rt < ROWT; ++rt) {
            const int wt = EVEN ? ((wave >> 1) * 2 + rt) : wave;
#pragma unroll
            for (int s2 = 0; s2 < 2; ++s2)
                areg[rt][s2] = *(const s16x8*)(wsrc + (wt * 16 + ln) * 64 + s2 * 32 + q * 8);
        }

        // T-form next u (writes sTn) — overlaps with MFMA below in the pipes
        if (uu < 15) tform(uu + 1, sTn);

        // MFMA from sTc
#pragma unroll
        for (int ci = 0; ci < COLT; ++ci) {
            const int c = EVEN ? ((wave & 1) * COLT + ci) : ci;
            s16x8 bf0 = *(const s16x8*)&sTc[(c * 16 + ln) * 72 + q * 8];
            s16x8 bf1 = *(const s16x8*)&sTc[(c * 16 + ln) * 72 + 32 + q * 8];
#pragma unroll
            for (int rt = 0; rt < ROWT; ++rt) {
                acc[rt][ci] = __builtin_amdgcn_mfma_f32_16x16x32_bf16(
                    areg[rt][0], bf0, acc[rt][ci], 0, 0, 0);
                acc[rt][ci] = __builtin_amdgcn_mfma_f32_16x16x32_bf16(
                    areg[rt][1], bf1, acc[rt][ci], 0, 0, 0);
            }
        }
        __syncthreads();
    }

    // ---- epilogue: transposed partials [us][k][z][w]; w is the acc fast axis
    // -> one contiguous float4 store per fragment, and reduce_out reads become
    // lane-coalesced.
#pragma unroll
    for (int rt = 0; rt < ROWT; ++rt) {
        const int wt = EVEN ? ((wave >> 1) * 2 + rt) : wave;
#pragma unroll
        for (int ci = 0; ci < COLT; ++ci) {
            const int c = EVEN ? ((wave & 1) * COLT + ci) : ci;
            const int col = c * 16 + ln;
            const int z = col / K1, k = col - z * K1;
            float* op = partp + ((size_t)(usub * K1 + k) * 1024 + z0 + z) * 64
                        + wt * 16 + q * 4;
            *(f32x4*)op = acc[rt][ci];
        }
    }
}

__global__ __launch_bounds__(NTHREADS, 5) void tp_main(KArgs a)
{
    __shared__ __align__(16) char smem[SMEM_BYTES];

    const int bid = blockIdx.x;
    // heavy-first: p2,p10,p5,p7,p6 (256 ea, ZT16), then p1,p8,p3,p9,p4,p0 (128 ea, ZT32)
    const int starts[12] = {0, 256, 512, 768, 1024, 1280, 1408, 1536, 1664, 1792, 1920, 2048};
    int idx = 0;
#pragma unroll
    for (int i = 1; i < 12; ++i) idx += (bid >= starts[i]) ? 1 : 0;
    const int local = bid - starts[idx];

    // LDS/path = 512 + ZT*(UC*S1+4)*4 + 2*ZT*K1*144:
    //  c0/c1: 31040  c2: 32000  c3: 32000  c4: 22784  c5/c6: 31744
    //  c7: 32768  c8: 26624  c9/c10: 18432   (max 32768 -> 5 blocks/CU)
    switch (idx) {            //  M1 N1 K1 ZT S1 UC
        case 0:  run_path<1,5,5,16,28, 4>(a.x1[0], a.x2[2], a.Wb + (size_t) 2*262144, a.C[2],  a.part[2],  local, smem); break;
        case 1:  run_path<5,5,5,16,28, 4>(a.x1[2], a.x2[2], a.Wb + (size_t)10*262144, a.C[10], a.part[10], local, smem); break;
        case 2:  run_path<3,3,5,16,16, 8>(a.x1[1], a.x2[1], a.Wb + (size_t) 5*262144, a.C[5],  a.part[5],  local, smem); break;
        case 3:  run_path<5,1,5,16, 8,16>(a.x1[2], a.x2[0], a.Wb + (size_t) 7*262144, a.C[7],  a.part[7],  local, smem); break;
        case 4:  run_path<3,5,3,16,16, 8>(a.x1[1], a.x2[2], a.Wb + (size_t) 6*262144, a.C[6],  a.part[6],  local, smem); break;
        case 5:  run_path<1,3,3,32,12, 2>(a.x1[0], a.x2[1], a.Wb + (size_t) 1*262144, a.C[1],  a.part[1],  local, smem); break;
        case 6:  run_path<5,3,3,32,12, 2>(a.x1[2], a.x2[1], a.Wb + (size_t) 8*262144, a.C[8],  a.part[8],  local, smem); break;
        case 7:  run_path<3,1,3,32, 4, 8>(a.x1[1], a.x2[0], a.Wb + (size_t) 3*262144, a.C[3],  a.part[3],  local, smem); break;
        case 8:  run_path<5,5,1,32, 8,16>(a.x1[2], a.x2[2], a.Wb + (size_t) 9*262144, a.C[9],  a.part[9],  local, smem); break;
        case 9:  run_path<3,3,1,32, 4,16>(a.x1[1], a.x2[1], a.Wb + (size_t) 4*262144, a.C[4],  a.part[4],  local, smem); break;
        case 10: run_path<1,1,1,32, 4,16>(a.x1[0], a.x2[0], a.Wb + (size_t) 0*262144, a.C[0],  a.part[0],  local, smem); break;
        default: break;
    }
}

// ---------------- reduce: sum partials into out[z][w][9] ----------------
// partials are [us][k][1024 z][64 w] per path -> every load below is
// lane-coalesced (w = lane). usub split across the 4 waves, LDS combine.

struct RArgs {
    const float* part[11];
    float*       out;
};

__global__ __launch_bounds__(NTHREADS) void reduce_out(RArgs r)
{
    __shared__ float red[3 * 64 * 9];
    const int lane = threadIdx.x & 63, us = threadIdx.x >> 6;
    const int zw = blockIdx.x * 64 + lane;      // z*64+w
    const int z = zw >> 6, w = zw & 63;

    float o[9];
#pragma unroll
    for (int i = 0; i < 9; ++i) o[i] = 0.f;

    {   // l3=0 (slot 0), paths {0,4,9}, K1=1
        const int P[3] = {0, 4, 9};
#pragma unroll
        for (int pi = 0; pi < 3; ++pi)
            o[0] += r.part[P[pi]][((size_t)us * 1024 + z) * 64 + w];
    }
    {   // l3=1 (slots 1..3), paths {1,3,6,8}, K1=3
        const int P[4] = {1, 3, 6, 8};
#pragma unroll
        for (int pi = 0; pi < 4; ++pi) {
            const float* pp = r.part[P[pi]];
#pragma unroll
            for (int k = 0; k < 3; ++k)
                o[1 + k] += pp[((size_t)(us * 3 + k) * 1024 + z) * 64 + w];
        }
    }
    {   // l3=2 (slots 4..8), paths {2,5,7,10}, K1=5
        const int P[4] = {2, 5, 7, 10};
#pragma unroll
        for (int pi = 0; pi < 4; ++pi) {
            const float* pp = r.part[P[pi]];
#pragma unroll
            for (int k = 0; k < 5; ++k)
                o[4 + k] += pp[((size_t)(us * 5 + k) * 1024 + z) * 64 + w];
        }
    }

    if (us > 0) {
#pragma unroll
        for (int i = 0; i < 9; ++i) red[((us - 1) * 64 + lane) * 9 + i] = o[i];
    }
    __syncthreads();
    if (us == 0) {
#pragma unroll
        for (int i = 0; i < 9; ++i)
            o[i] += red[(0 * 64 + lane) * 9 + i]
                  + red[(1 * 64 + lane) * 9 + i]
                  + red[(2 * 64 + lane) * 9 + i];
        float* op = r.out + (size_t)zw * 9;
#pragma unroll
        for (int i = 0; i < 9; ++i) op[i] = o[i];
    }
}

// ---------------- launch ----------------

extern "C" void kernel_launch(void* const* d_in, const int* in_sizes, int n_in,
                              void* d_out, int out_size, void* d_ws, size_t ws_size,
                              hipStream_t stream)
{
    static const int cumK1[11] = {0, 1, 4, 9, 12, 13, 18, 21, 26, 29, 30}; // prefix of K1

    unsigned short* Wb = (unsigned short*)d_ws;                       // 5.77 MB
    float* partbase = (float*)((char*)d_ws + (6u << 20));             // 30.7 MB

    KArgs a;
    // dict order: x1_l0, x2_l0, x1_l1, x2_l1, x1_l2, x2_l2, W, C_0..C_10
    a.x1[0] = (const float*)d_in[0];
    a.x2[0] = (const float*)d_in[1];
    a.x1[1] = (const float*)d_in[2];
    a.x2[1] = (const float*)d_in[3];
    a.x1[2] = (const float*)d_in[4];
    a.x2[2] = (const float*)d_in[5];
    a.Wb = Wb;
    RArgs rr;
    for (int p = 0; p < 11; ++p) {
        a.C[p]    = (const float*)d_in[7 + p];
        a.part[p] = partbase + (size_t)cumK1[p] * 262144;   // 4*K1*1024*64 per path
        rr.part[p] = a.part[p];
    }
    rr.out = (float*)d_out;

    prep_w<<<dim3(720896 / NTHREADS), NTHREADS, 0, stream>>>((const float*)d_in[6], Wb);
    tp_main<<<dim3(2048), NTHREADS, 0, stream>>>(a);
    reduce_out<<<dim3(1024), NTHREADS, 0, stream>>>(rr);
}